// Round 2
// baseline (3027.877 us; speedup 1.0000x reference)
//
#include <hip/hip_runtime.h>
#include <hip/hip_bf16.h>
#include <math.h>

// Problem constants
#define BQ 8
#define C1N 512
#define N1 784          // 28*28
#define C2N 1024
#define M2 196          // 14*14
#define NROWS 6272      // 8*784
#define MEMN 20000
#define DIMK 1024
#define OUTHW 50176     // 224*224

// ---- order-preserving float <-> uint for atomicMin ----
static __device__ __forceinline__ unsigned int f2ord(float f) {
  unsigned int b = __float_as_uint(f);
  return (b & 0x80000000u) ? ~b : (b | 0x80000000u);
}
static __device__ __forceinline__ float ord2f(unsigned int u) {
  unsigned int b = (u & 0x80000000u) ? (u ^ 0x80000000u) : ~u;
  return __uint_as_float(b);
}

// ---- scrambled patchify flat-index decode ----
// Reference's patchify flattens per-batch in (kj, w, c, ki, h) row-major order:
//   L = (((kj*W + w)*C + c)*3 + ki)*H + h ; value = x[b, c, h+ki-1, w+kj-1] (0 if OOB)
static __device__ __forceinline__ float f1val(const float* __restrict__ x, int b, unsigned L) {
  unsigned h = L % 28u; unsigned t = L / 28u;
  unsigned ki = t % 3u; t /= 3u;
  unsigned c = t % 512u; t /= 512u;
  unsigned w = t % 28u; unsigned kj = t / 28u;
  unsigned y = h + ki - 1u;   // wraps to huge if -1
  unsigned xx = w + kj - 1u;
  if (y >= 28u || xx >= 28u) return 0.f;
  return x[(((size_t)b * 512u + c) * 28u + y) * 28u + xx];
}
static __device__ __forceinline__ float f2val(const float* __restrict__ x, int b, unsigned L) {
  unsigned h = L % 14u; unsigned t = L / 14u;
  unsigned ki = t % 3u; t /= 3u;
  unsigned c = t % 1024u; t /= 1024u;
  unsigned w = t % 14u; unsigned kj = t / 14u;
  unsigned y = h + ki - 1u;
  unsigned xx = w + kj - 1u;
  if (y >= 14u || xx >= 14u) return 0.f;
  return x[(((size_t)b * 1024u + c) * 14u + y) * 14u + xx];
}

// feats[b,n,j<512] = (sum_{u=0..8} F1[9*(512n+j)+u] + F1[...+4]) / 10
__global__ __launch_bounds__(256) void feat_a_kernel(const float* __restrict__ feat1,
                                                     float* __restrict__ featsT) {
  int id = blockIdx.x * 256 + threadIdx.x;
  if (id >= BQ * C1N * N1) return;
  int n = id % N1; int t = id / N1;
  int j = t % 512; int b = t / 512;
  unsigned L0 = 9u * (unsigned)(512 * n + j);
  float s = 0.f;
#pragma unroll
  for (int u = 0; u < 9; ++u) s += f1val(feat1, b, L0 + u);
  s += f1val(feat1, b, L0 + 4u);
  featsT[(size_t)j * NROWS + b * N1 + n] = s * 0.1f;
}

// H2[b,n2,i] = (1/18) sum_{u<18} F2[18*(512*n2+i)+u]; then bilinear 14x14->28x28 over n2 grid
__global__ __launch_bounds__(256) void feat_b_kernel(const float* __restrict__ feat2,
                                                     float* __restrict__ featsT) {
  __shared__ float H2[M2];
  const int b = blockIdx.x >> 9;
  const int i = blockIdx.x & 511;
  for (int n2 = threadIdx.x; n2 < M2; n2 += 256) {
    unsigned L0 = 18u * (unsigned)(512 * n2 + i);
    float s = 0.f;
#pragma unroll
    for (int u = 0; u < 18; ++u) s += f2val(feat2, b, L0 + u);
    H2[n2] = s * (1.0f / 18.0f);
  }
  __syncthreads();
  for (int n = threadIdx.x; n < N1; n += 256) {
    int y = n / 28, x = n % 28;
    float sy = 0.5f * (float)y - 0.25f;
    sy = fminf(fmaxf(sy, 0.f), 13.f);
    int y0 = (int)sy, y1 = min(y0 + 1, 13);
    float wy = sy - (float)y0;
    float sx = 0.5f * (float)x - 0.25f;
    sx = fminf(fmaxf(sx, 0.f), 13.f);
    int x0 = (int)sx, x1 = min(x0 + 1, 13);
    float wx = sx - (float)x0;
    float v0 = H2[y0 * 14 + x0] * (1.f - wy) + H2[y1 * 14 + x0] * wy;
    float v1 = H2[y0 * 14 + x1] * (1.f - wy) + H2[y1 * 14 + x1] * wy;
    featsT[(size_t)(512 + i) * NROWS + b * N1 + n] = v0 * (1.f - wx) + v1 * wx;
  }
}

// memT[k][n] = memory[n][k]
__global__ __launch_bounds__(256) void transpose_kernel(const float* __restrict__ memory,
                                                        float* __restrict__ memT) {
  __shared__ float tile[32][33];
  const int n0 = blockIdx.x * 32;
  const int k0 = blockIdx.y * 32;
  const int ct = threadIdx.x & 31;
  const int rt = threadIdx.x >> 5;
#pragma unroll
  for (int i = 0; i < 4; ++i) {
    int r = rt + i * 8;
    tile[r][ct] = memory[(size_t)(n0 + r) * DIMK + k0 + ct];
  }
  __syncthreads();
#pragma unroll
  for (int i = 0; i < 4; ++i) {
    int r = rt + i * 8;
    memT[(size_t)(k0 + r) * MEMN + n0 + ct] = tile[ct][r];
  }
}

__global__ __launch_bounds__(256) void mnorm_kernel(const float* __restrict__ memory,
                                                    float* __restrict__ mnorm) {
  __shared__ float red[4];
  const int row = blockIdx.x;
  const float4 v = *(const float4*)&memory[(size_t)row * DIMK + threadIdx.x * 4];
  float s = v.x * v.x + v.y * v.y + v.z * v.z + v.w * v.w;
#pragma unroll
  for (int off = 32; off; off >>= 1) s += __shfl_down(s, off, 64);
  if ((threadIdx.x & 63) == 0) red[threadIdx.x >> 6] = s;
  __syncthreads();
  if (threadIdx.x == 0) mnorm[row] = red[0] + red[1] + red[2] + red[3];
}

__global__ __launch_bounds__(256) void fnorm_kernel(const float* __restrict__ featsT,
                                                    float* __restrict__ fnorm) {
  int row = blockIdx.x * 256 + threadIdx.x;
  if (row >= NROWS) return;
  float s = 0.f;
  for (int k = 0; k < DIMK; ++k) {
    float v = featsT[(size_t)k * NROWS + row];
    s += v * v;
  }
  fnorm[row] = s;
}

// C = feats * memory^T tile 128x128, BK=32; per-row min of (||m||^2 - 2C) -> atomicMin
template <bool KMAJOR>
__global__ __launch_bounds__(256) void dist_min_kernel(const float* __restrict__ featsT,
                                                       const float* __restrict__ Bmat,
                                                       const float* __restrict__ mnorm,
                                                       unsigned int* __restrict__ minu) {
  __shared__ __align__(16) float As[32][128];
  __shared__ __align__(16) float Bs[32][128];
  __shared__ float red[16][128];
  const int t = threadIdx.x;
  const int row0 = blockIdx.y * 128;
  const int col0 = blockIdx.x * 128;
  const int tm = t & 15, tn = t >> 4;
  float acc[8][8];
#pragma unroll
  for (int r = 0; r < 8; ++r)
#pragma unroll
    for (int c = 0; c < 8; ++c) acc[r][c] = 0.f;

  for (int k0 = 0; k0 < DIMK; k0 += 32) {
#pragma unroll
    for (int i = 0; i < 4; ++i) {
      int lin = t * 4 + i * 1024;
      int kk = lin >> 7, m = lin & 127;
      *(float4*)&As[kk][m] = *(const float4*)&featsT[(size_t)(k0 + kk) * NROWS + row0 + m];
    }
    if (KMAJOR) {
#pragma unroll
      for (int i = 0; i < 4; ++i) {
        int lin = t * 4 + i * 1024;
        int kk = lin >> 7, n = lin & 127;
        int gn = col0 + n;
        float4 v = make_float4(0.f, 0.f, 0.f, 0.f);
        if (gn < MEMN) v = *(const float4*)&Bmat[(size_t)(k0 + kk) * MEMN + gn];
        *(float4*)&Bs[kk][n] = v;
      }
    } else {
      int n = t & 127, kq = (t >> 7) * 16;
      int gn = col0 + n;
#pragma unroll
      for (int i = 0; i < 4; ++i) {
        float4 v = make_float4(0.f, 0.f, 0.f, 0.f);
        if (gn < MEMN) v = *(const float4*)&Bmat[(size_t)gn * DIMK + k0 + kq + i * 4];
        Bs[kq + i * 4 + 0][n] = v.x;
        Bs[kq + i * 4 + 1][n] = v.y;
        Bs[kq + i * 4 + 2][n] = v.z;
        Bs[kq + i * 4 + 3][n] = v.w;
      }
    }
    __syncthreads();
#pragma unroll
    for (int kk = 0; kk < 32; ++kk) {
      float a[8], bb[8];
      *(float4*)&a[0] = *(const float4*)&As[kk][tm * 4];
      *(float4*)&a[4] = *(const float4*)&As[kk][64 + tm * 4];
      *(float4*)&bb[0] = *(const float4*)&Bs[kk][tn * 4];
      *(float4*)&bb[4] = *(const float4*)&Bs[kk][64 + tn * 4];
#pragma unroll
      for (int r = 0; r < 8; ++r)
#pragma unroll
        for (int c = 0; c < 8; ++c) acc[r][c] = fmaf(a[r], bb[c], acc[r][c]);
    }
    __syncthreads();
  }

  float rmin[8];
#pragma unroll
  for (int r = 0; r < 8; ++r) rmin[r] = INFINITY;
#pragma unroll
  for (int c = 0; c < 8; ++c) {
    int col = (c < 4) ? (tn * 4 + c) : (64 + tn * 4 + c - 4);
    int gn = col0 + col;
    if (gn < MEMN) {
      float mn = mnorm[gn];
#pragma unroll
      for (int r = 0; r < 8; ++r) {
        float v = fmaf(-2.f, acc[r][c], mn);
        rmin[r] = fminf(rmin[r], v);
      }
    }
  }
#pragma unroll
  for (int r = 0; r < 8; ++r) {
    int rowl = (r < 4) ? (tm * 4 + r) : (64 + tm * 4 + r - 4);
    red[tn][rowl] = rmin[r];
  }
  __syncthreads();
  if (t < 128) {
    float v = INFINITY;
#pragma unroll
    for (int i = 0; i < 16; ++i) v = fminf(v, red[i][t]);
    atomicMin(&minu[row0 + t], f2ord(v));
  }
}

__global__ __launch_bounds__(256) void scores_kernel(const float* __restrict__ fnorm,
                                                     const unsigned int* __restrict__ minu,
                                                     float* __restrict__ scores) {
  int row = blockIdx.x * 256 + threadIdx.x;
  if (row >= NROWS) return;
  float d2 = fnorm[row] + ord2f(minu[row]);
  scores[row] = sqrtf(fmaxf(d2, 0.f));
}

__global__ __launch_bounds__(256) void image_max_kernel(const float* __restrict__ scores,
                                                        float* __restrict__ out) {
  __shared__ float red[4];
  const int b = blockIdx.x;
  float m = -INFINITY;
  for (int n = threadIdx.x; n < N1; n += 256) m = fmaxf(m, scores[b * N1 + n]);
#pragma unroll
  for (int off = 32; off; off >>= 1) m = fmaxf(m, __shfl_down(m, off, 64));
  if ((threadIdx.x & 63) == 0) red[threadIdx.x >> 6] = m;
  __syncthreads();
  if (threadIdx.x == 0) out[b] = fmaxf(fmaxf(red[0], red[1]), fmaxf(red[2], red[3]));
}

__global__ __launch_bounds__(256) void upsample_kernel(const float* __restrict__ scores,
                                                       float* __restrict__ out) {
  int o = blockIdx.x * 256 + threadIdx.x;
  if (o >= BQ * OUTHW) return;
  int b = o / OUTHW, rem = o % OUTHW;
  int oy = rem / 224, ox = rem % 224;
  float sy = ((float)oy + 0.5f) * 0.125f - 0.5f;
  sy = fminf(fmaxf(sy, 0.f), 27.f);
  int y0 = (int)sy, y1 = min(y0 + 1, 27);
  float wy = sy - (float)y0;
  float sx = ((float)ox + 0.5f) * 0.125f - 0.5f;
  sx = fminf(fmaxf(sx, 0.f), 27.f);
  int x0 = (int)sx, x1 = min(x0 + 1, 27);
  float wx = sx - (float)x0;
  const float* s = scores + b * N1;
  float v0 = s[y0 * 28 + x0] * (1.f - wy) + s[y1 * 28 + x0] * wy;
  float v1 = s[y0 * 28 + x1] * (1.f - wy) + s[y1 * 28 + x1] * wy;
  out[BQ + o] = v0 * (1.f - wx) + v1 * wx;
}

extern "C" void kernel_launch(void* const* d_in, const int* in_sizes, int n_in,
                              void* d_out, int out_size, void* d_ws, size_t ws_size,
                              hipStream_t stream) {
  const float* feat1 = (const float*)d_in[0];
  const float* feat2 = (const float*)d_in[1];
  const float* memory = (const float*)d_in[2];
  float* out = (float*)d_out;

  char* ws = (char*)d_ws;
  size_t off = 0;
  auto wsalloc = [&](size_t bytes) {
    void* p = ws + off;
    off += (bytes + 255) & ~(size_t)255;
    return p;
  };
  float* featsT = (float*)wsalloc((size_t)DIMK * NROWS * 4);
  float* mnorm = (float*)wsalloc((size_t)MEMN * 4);
  float* fnorm = (float*)wsalloc((size_t)NROWS * 4);
  unsigned int* minu = (unsigned int*)wsalloc((size_t)NROWS * 4);
  float* scores = (float*)wsalloc((size_t)NROWS * 4);
  size_t base = off;
  float* memT = (float*)(ws + base);
  const bool kmajor = (ws_size >= base + (size_t)DIMK * MEMN * 4);

  feat_a_kernel<<<(BQ * C1N * N1 + 255) / 256, 256, 0, stream>>>(feat1, featsT);
  feat_b_kernel<<<BQ * C1N, 256, 0, stream>>>(feat2, featsT);
  fnorm_kernel<<<(NROWS + 255) / 256, 256, 0, stream>>>(featsT, fnorm);
  mnorm_kernel<<<MEMN, 256, 0, stream>>>(memory, mnorm);
  hipMemsetAsync(minu, 0xFF, (size_t)NROWS * 4, stream);

  dim3 dg((MEMN + 127) / 128, (NROWS + 127) / 128);
  if (kmajor) {
    transpose_kernel<<<dim3(MEMN / 32, DIMK / 32), 256, 0, stream>>>(memory, memT);
    dist_min_kernel<true><<<dg, 256, 0, stream>>>(featsT, memT, mnorm, minu);
  } else {
    dist_min_kernel<false><<<dg, 256, 0, stream>>>(featsT, memory, mnorm, minu);
  }

  scores_kernel<<<(NROWS + 255) / 256, 256, 0, stream>>>(fnorm, minu, scores);
  image_max_kernel<<<BQ, 256, 0, stream>>>(scores, out);
  upsample_kernel<<<(BQ * OUTHW + 255) / 256, 256, 0, stream>>>(scores, out);
}

// Round 3
// 577.641 us; speedup vs baseline: 5.2418x; 5.2418x over previous
//
#include <hip/hip_runtime.h>
#include <hip/hip_bf16.h>
#include <math.h>

// Problem constants
#define BQ 8
#define C1N 512
#define N1 784          // 28*28
#define C2N 1024
#define M2 196          // 14*14
#define NROWS 6272      // 8*784
#define MEMN 20000
#define MEMNP 20096     // padded to 157*128
#define DIMK 1024
#define OUTHW 50176     // 224*224

typedef unsigned short u16;
typedef __attribute__((ext_vector_type(8))) short short8v;
typedef __attribute__((ext_vector_type(4))) float f32x4;

// ---- order-preserving float <-> uint for atomicMin ----
static __device__ __forceinline__ unsigned int f2ord(float f) {
  unsigned int b = __float_as_uint(f);
  return (b & 0x80000000u) ? ~b : (b | 0x80000000u);
}
static __device__ __forceinline__ float ord2f(unsigned int u) {
  unsigned int b = (u & 0x80000000u) ? (u ^ 0x80000000u) : ~u;
  return __uint_as_float(b);
}

// ---- bf16 helpers (RNE) ----
static __device__ __forceinline__ u16 f2bf(float x) {
  unsigned u = __float_as_uint(x);
  u += 0x7FFFu + ((u >> 16) & 1u);
  return (u16)(u >> 16);
}
static __device__ __forceinline__ float bf2f(u16 b) {
  return __uint_as_float(((unsigned)b) << 16);
}

// ---- async global->LDS (16B per lane, dest = wave-uniform base + lane*16) ----
static __device__ __forceinline__ void gload16(const void* g, void* l) {
  __builtin_amdgcn_global_load_lds((const __attribute__((address_space(1))) void*)g,
                                   (__attribute__((address_space(3))) void*)l, 16, 0, 0);
}

// ---- scrambled patchify flat-index decode ----
// Reference's patchify flattens per-batch in (kj, w, c, ki, h) row-major order:
//   L = (((kj*W + w)*C + c)*3 + ki)*H + h ; value = x[b, c, h+ki-1, w+kj-1] (0 if OOB)
static __device__ __forceinline__ float f1val(const float* __restrict__ x, int b, unsigned L) {
  unsigned h = L % 28u; unsigned t = L / 28u;
  unsigned ki = t % 3u; t /= 3u;
  unsigned c = t % 512u; t /= 512u;
  unsigned w = t % 28u; unsigned kj = t / 28u;
  unsigned y = h + ki - 1u;   // wraps to huge if -1
  unsigned xx = w + kj - 1u;
  if (y >= 28u || xx >= 28u) return 0.f;
  return x[(((size_t)b * 512u + c) * 28u + y) * 28u + xx];
}
static __device__ __forceinline__ float f2val(const float* __restrict__ x, int b, unsigned L) {
  unsigned h = L % 14u; unsigned t = L / 14u;
  unsigned ki = t % 3u; t /= 3u;
  unsigned c = t % 1024u; t /= 1024u;
  unsigned w = t % 14u; unsigned kj = t / 14u;
  unsigned y = h + ki - 1u;
  unsigned xx = w + kj - 1u;
  if (y >= 14u || xx >= 14u) return 0.f;
  return x[(((size_t)b * 1024u + c) * 14u + y) * 14u + xx];
}

// ================= MFMA path (bf16 feats, row-major) =================

// feats[b,n,j<512] = (sum_{u=0..8} F1[9*(512n+j)+u] + F1[...+4]) / 10 ; j fastest -> coalesced
__global__ __launch_bounds__(256) void feat_a_bf(const float* __restrict__ feat1,
                                                 u16* __restrict__ featsR) {
  int id = blockIdx.x * 256 + threadIdx.x;
  if (id >= BQ * N1 * C1N) return;
  int j = id & 511; int t = id >> 9;
  int n = t % N1; int b = t / N1;
  unsigned L0 = 9u * (unsigned)(512 * n + j);
  float s = 0.f;
#pragma unroll
  for (int u = 0; u < 9; ++u) s += f1val(feat1, b, L0 + u);
  s += f1val(feat1, b, L0 + 4u);
  featsR[(size_t)(b * N1 + n) * DIMK + j] = f2bf(s * 0.1f);
}

// H2all[b][n2][i] = (1/18) sum_{u<18} F2[18*(512*n2+i)+u]
__global__ __launch_bounds__(256) void feat_b_stage1(const float* __restrict__ feat2,
                                                     float* __restrict__ H2all) {
  int b = blockIdx.x / M2;
  int n2 = blockIdx.x % M2;
  for (int i = threadIdx.x; i < 512; i += 256) {
    unsigned L0 = 18u * (unsigned)(512 * n2 + i);
    float s = 0.f;
#pragma unroll
    for (int u = 0; u < 18; ++u) s += f2val(feat2, b, L0 + u);
    H2all[((size_t)b * M2 + n2) * 512 + i] = s * (1.0f / 18.0f);
  }
}

// bilinear 14x14 -> 28x28 over the n2 grid, write feats[b,n,512+i]
__global__ __launch_bounds__(256) void feat_b_stage2(const float* __restrict__ H2all,
                                                     u16* __restrict__ featsR) {
  int bn = blockIdx.x;
  int b = bn / N1, n = bn % N1;
  int y = n / 28, x = n % 28;
  float sy = 0.5f * (float)y - 0.25f;
  sy = fminf(fmaxf(sy, 0.f), 13.f);
  int y0 = (int)sy, y1 = min(y0 + 1, 13);
  float wy = sy - (float)y0;
  float sx = 0.5f * (float)x - 0.25f;
  sx = fminf(fmaxf(sx, 0.f), 13.f);
  int x0 = (int)sx, x1 = min(x0 + 1, 13);
  float wx = sx - (float)x0;
  float w00 = (1.f - wy) * (1.f - wx), w10 = wy * (1.f - wx);
  float w01 = (1.f - wy) * wx, w11 = wy * wx;
  const float* h00 = H2all + ((size_t)b * M2 + y0 * 14 + x0) * 512;
  const float* h10 = H2all + ((size_t)b * M2 + y1 * 14 + x0) * 512;
  const float* h01 = H2all + ((size_t)b * M2 + y0 * 14 + x1) * 512;
  const float* h11 = H2all + ((size_t)b * M2 + y1 * 14 + x1) * 512;
  u16* dst = featsR + (size_t)bn * DIMK + 512;
  for (int i = threadIdx.x; i < 512; i += 256) {
    float v = w00 * h00[i] + w10 * h10[i] + w01 * h01[i] + w11 * h11[i];
    dst[i] = f2bf(v);
  }
}

// memory fp32 -> bf16, padded rows [MEMN, MEMNP) = 0
__global__ __launch_bounds__(256) void memconv(const float* __restrict__ mem,
                                               u16* __restrict__ memB) {
  size_t id = (size_t)blockIdx.x * 256 + threadIdx.x;
  size_t e0 = id * 8;
  if (e0 >= (size_t)MEMNP * DIMK) return;
  int n = (int)(e0 >> 10);
  short8v o;
  if (n < MEMN) {
    float4 a = *(const float4*)&mem[e0];
    float4 b = *(const float4*)&mem[e0 + 4];
    o[0] = (short)f2bf(a.x); o[1] = (short)f2bf(a.y);
    o[2] = (short)f2bf(a.z); o[3] = (short)f2bf(a.w);
    o[4] = (short)f2bf(b.x); o[5] = (short)f2bf(b.y);
    o[6] = (short)f2bf(b.z); o[7] = (short)f2bf(b.w);
  } else {
#pragma unroll
    for (int i = 0; i < 8; ++i) o[i] = 0;
  }
  *(short8v*)&memB[e0] = o;
}

// fnorm from bf16 feats: 1 wave per row, 16 elems/lane
__global__ __launch_bounds__(256) void fnorm_bf(const u16* __restrict__ featsR,
                                                float* __restrict__ fnorm) {
  int row = blockIdx.x * 4 + (threadIdx.x >> 6);
  int lane = threadIdx.x & 63;
  const short8v* p = (const short8v*)(featsR + (size_t)row * DIMK) + lane * 2;
  float s = 0.f;
#pragma unroll
  for (int q = 0; q < 2; ++q) {
    short8v v = p[q];
#pragma unroll
    for (int i = 0; i < 8; ++i) {
      float f = bf2f((u16)v[i]);
      s = fmaf(f, f, s);
    }
  }
#pragma unroll
  for (int off = 32; off; off >>= 1) s += __shfl_down(s, off, 64);
  if (lane == 0) fnorm[row] = s;
}

__global__ __launch_bounds__(256) void mnorm_kernel(const float* __restrict__ memory,
                                                    float* __restrict__ mnorm) {
  __shared__ float red[4];
  const int row = blockIdx.x;
  const float4 v = *(const float4*)&memory[(size_t)row * DIMK + threadIdx.x * 4];
  float s = v.x * v.x + v.y * v.y + v.z * v.z + v.w * v.w;
#pragma unroll
  for (int off = 32; off; off >>= 1) s += __shfl_down(s, off, 64);
  if ((threadIdx.x & 63) == 0) red[threadIdx.x >> 6] = s;
  __syncthreads();
  if (threadIdx.x == 0) mnorm[row] = red[0] + red[1] + red[2] + red[3];
}

// ---- bf16 MFMA distance GEMM + row-min (m97 structure: 128x128 tile, BK=32) ----
__global__ __launch_bounds__(256) void dist_min_mfma(const u16* __restrict__ A,
                                                     const u16* __restrict__ B,
                                                     const float* __restrict__ mnorm,
                                                     unsigned int* __restrict__ minu) {
  __shared__ __align__(16) u16 As[128 * 32];
  __shared__ __align__(16) u16 Bs[128 * 32];
  const int t = threadIdx.x;
  const int wave = t >> 6, lane = t & 63;
  const int row0 = blockIdx.y * 128, col0 = blockIdx.x * 128;
  const int wr = (wave >> 1) * 64, wc = (wave & 1) * 64;

  f32x4 acc[4][4];
#pragma unroll
  for (int i = 0; i < 4; ++i)
#pragma unroll
    for (int j = 0; j < 4; ++j) acc[i][j] = (f32x4){0.f, 0.f, 0.f, 0.f};

  // staging: wave w stages rows [w*32, w*32+32) of both tiles (two 16-row chunks)
  const int srow = wave * 32 + (lane >> 2);
  const int skk = (lane & 3) * 8;
  const u16* ag = A + (size_t)(row0 + srow) * DIMK + skk;
  const u16* bg = B + (size_t)(col0 + srow) * DIMK + skk;
  u16* al = &As[wave * 1024];
  u16* bl = &Bs[wave * 1024];

  const int frow = lane & 15;
  const int fko = (lane >> 4) * 8;   // same k-mapping for A and B fragments

  for (int k0 = 0; k0 < DIMK; k0 += 32) {
    gload16(ag + k0, al);
    gload16(ag + k0 + 16 * DIMK, al + 512);
    gload16(bg + k0, bl);
    gload16(bg + k0 + 16 * DIMK, bl + 512);
    __syncthreads();
    short8v a[4], b[4];
#pragma unroll
    for (int mi = 0; mi < 4; ++mi)
      a[mi] = *(const short8v*)&As[(wr + mi * 16 + frow) * 32 + fko];
#pragma unroll
    for (int ni = 0; ni < 4; ++ni)
      b[ni] = *(const short8v*)&Bs[(wc + ni * 16 + frow) * 32 + fko];
#pragma unroll
    for (int mi = 0; mi < 4; ++mi)
#pragma unroll
      for (int ni = 0; ni < 4; ++ni)
        acc[mi][ni] = __builtin_amdgcn_mfma_f32_16x16x32_bf16(a[mi], b[ni], acc[mi][ni], 0, 0, 0);
    __syncthreads();
  }

  // epilogue: v = mnorm[col] - 2*dot ; row-min across the 16-lane group
  float cmn[4];
#pragma unroll
  for (int ni = 0; ni < 4; ++ni) {
    int gn = col0 + wc + ni * 16 + frow;
    cmn[ni] = (gn < MEMN) ? mnorm[gn] : INFINITY;
  }
#pragma unroll
  for (int mi = 0; mi < 4; ++mi) {
#pragma unroll
    for (int r = 0; r < 4; ++r) {
      float v = INFINITY;
#pragma unroll
      for (int ni = 0; ni < 4; ++ni)
        v = fminf(v, fmaf(-2.f, acc[mi][ni][r], cmn[ni]));
#pragma unroll
      for (int off = 1; off < 16; off <<= 1)
        v = fminf(v, __shfl_xor(v, off, 64));
      if (frow == 0) {
        int grow = row0 + wr + mi * 16 + (lane >> 4) * 4 + r;
        atomicMin(&minu[grow], f2ord(v));
      }
    }
  }
}

// ================= fallback fp32 path (round-2, ws-constrained) =================

__global__ __launch_bounds__(256) void feat_a_kernel(const float* __restrict__ feat1,
                                                     float* __restrict__ featsT) {
  int id = blockIdx.x * 256 + threadIdx.x;
  if (id >= BQ * C1N * N1) return;
  int n = id % N1; int t = id / N1;
  int j = t % 512; int b = t / 512;
  unsigned L0 = 9u * (unsigned)(512 * n + j);
  float s = 0.f;
#pragma unroll
  for (int u = 0; u < 9; ++u) s += f1val(feat1, b, L0 + u);
  s += f1val(feat1, b, L0 + 4u);
  featsT[(size_t)j * NROWS + b * N1 + n] = s * 0.1f;
}

__global__ __launch_bounds__(256) void feat_b_kernel(const float* __restrict__ feat2,
                                                     float* __restrict__ featsT) {
  __shared__ float H2[M2];
  const int b = blockIdx.x >> 9;
  const int i = blockIdx.x & 511;
  for (int n2 = threadIdx.x; n2 < M2; n2 += 256) {
    unsigned L0 = 18u * (unsigned)(512 * n2 + i);
    float s = 0.f;
#pragma unroll
    for (int u = 0; u < 18; ++u) s += f2val(feat2, b, L0 + u);
    H2[n2] = s * (1.0f / 18.0f);
  }
  __syncthreads();
  for (int n = threadIdx.x; n < N1; n += 256) {
    int y = n / 28, x = n % 28;
    float sy = 0.5f * (float)y - 0.25f;
    sy = fminf(fmaxf(sy, 0.f), 13.f);
    int y0 = (int)sy, y1 = min(y0 + 1, 13);
    float wy = sy - (float)y0;
    float sx = 0.5f * (float)x - 0.25f;
    sx = fminf(fmaxf(sx, 0.f), 13.f);
    int x0 = (int)sx, x1 = min(x0 + 1, 13);
    float wx = sx - (float)x0;
    float v0 = H2[y0 * 14 + x0] * (1.f - wy) + H2[y1 * 14 + x0] * wy;
    float v1 = H2[y0 * 14 + x1] * (1.f - wy) + H2[y1 * 14 + x1] * wy;
    featsT[(size_t)(512 + i) * NROWS + b * N1 + n] = v0 * (1.f - wx) + v1 * wx;
  }
}

__global__ __launch_bounds__(256) void fnorm_kernel(const float* __restrict__ featsT,
                                                    float* __restrict__ fnorm) {
  int row = blockIdx.x * 256 + threadIdx.x;
  if (row >= NROWS) return;
  float s = 0.f;
  for (int k = 0; k < DIMK; ++k) {
    float v = featsT[(size_t)k * NROWS + row];
    s += v * v;
  }
  fnorm[row] = s;
}

__global__ __launch_bounds__(256) void dist_min_kernel(const float* __restrict__ featsT,
                                                       const float* __restrict__ Bmat,
                                                       const float* __restrict__ mnorm,
                                                       unsigned int* __restrict__ minu) {
  __shared__ __align__(16) float As2[32][128];
  __shared__ __align__(16) float Bs2[32][128];
  __shared__ float red[16][128];
  const int t = threadIdx.x;
  const int row0 = blockIdx.y * 128;
  const int col0 = blockIdx.x * 128;
  const int tm = t & 15, tn = t >> 4;
  float acc[8][8];
#pragma unroll
  for (int r = 0; r < 8; ++r)
#pragma unroll
    for (int c = 0; c < 8; ++c) acc[r][c] = 0.f;

  for (int k0 = 0; k0 < DIMK; k0 += 32) {
#pragma unroll
    for (int i = 0; i < 4; ++i) {
      int lin = t * 4 + i * 1024;
      int kk = lin >> 7, m = lin & 127;
      *(float4*)&As2[kk][m] = *(const float4*)&featsT[(size_t)(k0 + kk) * NROWS + row0 + m];
    }
    {
      int n = t & 127, kq = (t >> 7) * 16;
      int gn = col0 + n;
#pragma unroll
      for (int i = 0; i < 4; ++i) {
        float4 v = make_float4(0.f, 0.f, 0.f, 0.f);
        if (gn < MEMN) v = *(const float4*)&Bmat[(size_t)gn * DIMK + k0 + kq + i * 4];
        Bs2[kq + i * 4 + 0][n] = v.x;
        Bs2[kq + i * 4 + 1][n] = v.y;
        Bs2[kq + i * 4 + 2][n] = v.z;
        Bs2[kq + i * 4 + 3][n] = v.w;
      }
    }
    __syncthreads();
#pragma unroll
    for (int kk = 0; kk < 32; ++kk) {
      float a[8], bb[8];
      *(float4*)&a[0] = *(const float4*)&As2[kk][tm * 4];
      *(float4*)&a[4] = *(const float4*)&As2[kk][64 + tm * 4];
      *(float4*)&bb[0] = *(const float4*)&Bs2[kk][tn * 4];
      *(float4*)&bb[4] = *(const float4*)&Bs2[kk][64 + tn * 4];
#pragma unroll
      for (int r = 0; r < 8; ++r)
#pragma unroll
        for (int c = 0; c < 8; ++c) acc[r][c] = fmaf(a[r], bb[c], acc[r][c]);
    }
    __syncthreads();
  }

  float rmin[8];
#pragma unroll
  for (int r = 0; r < 8; ++r) rmin[r] = INFINITY;
#pragma unroll
  for (int c = 0; c < 8; ++c) {
    int col = (c < 4) ? (tn * 4 + c) : (64 + tn * 4 + c - 4);
    int gn = col0 + col;
    if (gn < MEMN) {
      float mn = mnorm[gn];
#pragma unroll
      for (int r = 0; r < 8; ++r) {
        float v = fmaf(-2.f, acc[r][c], mn);
        rmin[r] = fminf(rmin[r], v);
      }
    }
  }
#pragma unroll
  for (int r = 0; r < 8; ++r) {
    int rowl = (r < 4) ? (tm * 4 + r) : (64 + tm * 4 + r - 4);
    red[tn][rowl] = rmin[r];
  }
  __syncthreads();
  if (t < 128) {
    float v = INFINITY;
#pragma unroll
    for (int i = 0; i < 16; ++i) v = fminf(v, red[i][t]);
    atomicMin(&minu[row0 + t], f2ord(v));
  }
}

// ================= shared epilogue kernels =================

__global__ __launch_bounds__(256) void scores_kernel(const float* __restrict__ fnorm,
                                                     const unsigned int* __restrict__ minu,
                                                     float* __restrict__ scores) {
  int row = blockIdx.x * 256 + threadIdx.x;
  if (row >= NROWS) return;
  float d2 = fnorm[row] + ord2f(minu[row]);
  scores[row] = sqrtf(fmaxf(d2, 0.f));
}

__global__ __launch_bounds__(256) void image_max_kernel(const float* __restrict__ scores,
                                                        float* __restrict__ out) {
  __shared__ float red[4];
  const int b = blockIdx.x;
  float m = -INFINITY;
  for (int n = threadIdx.x; n < N1; n += 256) m = fmaxf(m, scores[b * N1 + n]);
#pragma unroll
  for (int off = 32; off; off >>= 1) m = fmaxf(m, __shfl_down(m, off, 64));
  if ((threadIdx.x & 63) == 0) red[threadIdx.x >> 6] = m;
  __syncthreads();
  if (threadIdx.x == 0) out[b] = fmaxf(fmaxf(red[0], red[1]), fmaxf(red[2], red[3]));
}

__global__ __launch_bounds__(256) void upsample_kernel(const float* __restrict__ scores,
                                                       float* __restrict__ out) {
  int o = blockIdx.x * 256 + threadIdx.x;
  if (o >= BQ * OUTHW) return;
  int b = o / OUTHW, rem = o % OUTHW;
  int oy = rem / 224, ox = rem % 224;
  float sy = ((float)oy + 0.5f) * 0.125f - 0.5f;
  sy = fminf(fmaxf(sy, 0.f), 27.f);
  int y0 = (int)sy, y1 = min(y0 + 1, 27);
  float wy = sy - (float)y0;
  float sx = ((float)ox + 0.5f) * 0.125f - 0.5f;
  sx = fminf(fmaxf(sx, 0.f), 27.f);
  int x0 = (int)sx, x1 = min(x0 + 1, 27);
  float wx = sx - (float)x0;
  const float* s = scores + b * N1;
  float v0 = s[y0 * 28 + x0] * (1.f - wy) + s[y1 * 28 + x0] * wy;
  float v1 = s[y0 * 28 + x1] * (1.f - wy) + s[y1 * 28 + x1] * wy;
  out[BQ + o] = v0 * (1.f - wx) + v1 * wx;
}

extern "C" void kernel_launch(void* const* d_in, const int* in_sizes, int n_in,
                              void* d_out, int out_size, void* d_ws, size_t ws_size,
                              hipStream_t stream) {
  const float* feat1 = (const float*)d_in[0];
  const float* feat2 = (const float*)d_in[1];
  const float* memory = (const float*)d_in[2];
  float* out = (float*)d_out;

  char* ws = (char*)d_ws;
  size_t off = 0;
  auto wsalloc = [&](size_t bytes) {
    void* p = ws + off;
    off += (bytes + 255) & ~(size_t)255;
    return p;
  };

  // MFMA-path footprint
  const size_t featsR_b = (size_t)NROWS * DIMK * 2;
  const size_t memB_b = (size_t)MEMNP * DIMK * 2;
  const size_t H2_b = (size_t)BQ * M2 * 512 * 4;
  const size_t small_b = ((size_t)MEMN * 4 + 255 & ~(size_t)255) + 3 * (((size_t)NROWS * 4 + 255) & ~(size_t)255);
  const size_t need_mfma = featsR_b + memB_b + H2_b + small_b + 4096;

  if (ws_size >= need_mfma) {
    u16* featsR = (u16*)wsalloc(featsR_b);
    u16* memB = (u16*)wsalloc(memB_b);
    float* H2all = (float*)wsalloc(H2_b);
    float* mnorm = (float*)wsalloc((size_t)MEMN * 4);
    float* fnorm = (float*)wsalloc((size_t)NROWS * 4);
    unsigned int* minu = (unsigned int*)wsalloc((size_t)NROWS * 4);
    float* scores = (float*)wsalloc((size_t)NROWS * 4);

    feat_a_bf<<<(BQ * N1 * C1N) / 256, 256, 0, stream>>>(feat1, featsR);
    feat_b_stage1<<<BQ * M2, 256, 0, stream>>>(feat2, H2all);
    feat_b_stage2<<<BQ * N1, 256, 0, stream>>>(H2all, featsR);
    memconv<<<(MEMNP * DIMK / 8 + 255) / 256, 256, 0, stream>>>(memory, memB);
    fnorm_bf<<<NROWS / 4, 256, 0, stream>>>(featsR, fnorm);
    mnorm_kernel<<<MEMN, 256, 0, stream>>>(memory, mnorm);
    hipMemsetAsync(minu, 0xFF, (size_t)NROWS * 4, stream);

    dim3 dg(MEMNP / 128, NROWS / 128);
    dist_min_mfma<<<dg, 256, 0, stream>>>(featsR, memB, mnorm, minu);

    scores_kernel<<<(NROWS + 255) / 256, 256, 0, stream>>>(fnorm, minu, scores);
    image_max_kernel<<<BQ, 256, 0, stream>>>(scores, out);
    upsample_kernel<<<(BQ * OUTHW + 255) / 256, 256, 0, stream>>>(scores, out);
  } else {
    // fallback: round-2 fp32 path
    float* featsT = (float*)wsalloc((size_t)DIMK * NROWS * 4);
    float* mnorm = (float*)wsalloc((size_t)MEMN * 4);
    float* fnorm = (float*)wsalloc((size_t)NROWS * 4);
    unsigned int* minu = (unsigned int*)wsalloc((size_t)NROWS * 4);
    float* scores = (float*)wsalloc((size_t)NROWS * 4);

    feat_a_kernel<<<(BQ * C1N * N1 + 255) / 256, 256, 0, stream>>>(feat1, featsT);
    feat_b_kernel<<<BQ * C1N, 256, 0, stream>>>(feat2, featsT);
    fnorm_kernel<<<(NROWS + 255) / 256, 256, 0, stream>>>(featsT, fnorm);
    mnorm_kernel<<<MEMN, 256, 0, stream>>>(memory, mnorm);
    hipMemsetAsync(minu, 0xFF, (size_t)NROWS * 4, stream);

    dim3 dg((MEMN + 127) / 128, (NROWS + 127) / 128);
    dist_min_kernel<<<dg, 256, 0, stream>>>(featsT, memory, mnorm, minu);

    scores_kernel<<<(NROWS + 255) / 256, 256, 0, stream>>>(fnorm, minu, scores);
    image_max_kernel<<<BQ, 256, 0, stream>>>(scores, out);
    upsample_kernel<<<(BQ * OUTHW + 255) / 256, 256, 0, stream>>>(scores, out);
  }
}

// Round 4
// 462.952 us; speedup vs baseline: 6.5404x; 1.2477x over previous
//
#include <hip/hip_runtime.h>
#include <hip/hip_bf16.h>
#include <math.h>

// Problem constants
#define BQ 8
#define C1N 512
#define N1 784          // 28*28
#define C2N 1024
#define M2 196          // 14*14
#define NROWS 6272      // 8*784 = 49*128
#define MEMN 20000
#define MEMNP 20096     // 157*128
#define DIMK 1024
#define NKB 32          // K blocks of 32
#define OUTHW 50176     // 224*224
#define NTILEA 49
#define NTILEB 157
#define NWG (NTILEB * NTILEA)   // 7693

typedef unsigned short u16;
typedef __attribute__((ext_vector_type(8))) short short8v;
typedef __attribute__((ext_vector_type(4))) float f32x4;

// ---- order-preserving float <-> uint for atomicMin ----
static __device__ __forceinline__ unsigned int f2ord(float f) {
  unsigned int b = __float_as_uint(f);
  return (b & 0x80000000u) ? ~b : (b | 0x80000000u);
}
static __device__ __forceinline__ float ord2f(unsigned int u) {
  unsigned int b = (u & 0x80000000u) ? (u ^ 0x80000000u) : ~u;
  return __uint_as_float(b);
}

// ---- bf16 helpers (RNE) ----
static __device__ __forceinline__ u16 f2bf(float x) {
  unsigned u = __float_as_uint(x);
  u += 0x7FFFu + ((u >> 16) & 1u);
  return (u16)(u >> 16);
}
static __device__ __forceinline__ float bf2f(u16 b) {
  return __uint_as_float(((unsigned)b) << 16);
}

// ---- async global->LDS (16B per lane; LDS dest = uniform base + lane*16) ----
static __device__ __forceinline__ void gload16(const void* g, void* l) {
  __builtin_amdgcn_global_load_lds((const __attribute__((address_space(1))) void*)g,
                                   (__attribute__((address_space(3))) void*)l, 16, 0, 0);
}

// ---- tiled (k-major) element index ----
// layout: [tile][kb=32][c=4][row=128][e=8] ; element (grow=tile*128+row, k=kb*32+c*8+e)
static __device__ __forceinline__ size_t tiled_idx(int grow, int k) {
  int tile = grow >> 7, row = grow & 127;
  int kb = k >> 5, c = (k >> 3) & 3, e = k & 7;
  return (((size_t)(tile * NKB + kb) * 4 + c) * 128 + row) * 8 + e;
}

// ---- scrambled patchify flat-index decode ----
// Reference's patchify flattens per-batch in (kj, w, c, ki, h) row-major order:
//   L = (((kj*W + w)*C + c)*3 + ki)*H + h ; value = x[b, c, h+ki-1, w+kj-1] (0 if OOB)
static __device__ __forceinline__ float f1val(const float* __restrict__ x, int b, unsigned L) {
  unsigned h = L % 28u; unsigned t = L / 28u;
  unsigned ki = t % 3u; t /= 3u;
  unsigned c = t % 512u; t /= 512u;
  unsigned w = t % 28u; unsigned kj = t / 28u;
  unsigned y = h + ki - 1u;   // wraps to huge if -1
  unsigned xx = w + kj - 1u;
  if (y >= 28u || xx >= 28u) return 0.f;
  return x[(((size_t)b * 512u + c) * 28u + y) * 28u + xx];
}
static __device__ __forceinline__ float f2val(const float* __restrict__ x, int b, unsigned L) {
  unsigned h = L % 14u; unsigned t = L / 14u;
  unsigned ki = t % 3u; t /= 3u;
  unsigned c = t % 1024u; t /= 1024u;
  unsigned w = t % 14u; unsigned kj = t / 14u;
  unsigned y = h + ki - 1u;
  unsigned xx = w + kj - 1u;
  if (y >= 14u || xx >= 14u) return 0.f;
  return x[(((size_t)b * 1024u + c) * 14u + y) * 14u + xx];
}

// feats[b,n,j<512] = (sum_{u=0..8} F1[9*(512n+j)+u] + F1[...+4]) / 10  -> tiled layout
__global__ __launch_bounds__(256) void feat_a_bf(const float* __restrict__ feat1,
                                                 u16* __restrict__ At) {
  int id = blockIdx.x * 256 + threadIdx.x;
  if (id >= BQ * N1 * C1N) return;
  int j = id & 511; int t = id >> 9;
  int n = t % N1; int b = t / N1;
  unsigned L0 = 9u * (unsigned)(512 * n + j);
  float s = 0.f;
#pragma unroll
  for (int u = 0; u < 9; ++u) s += f1val(feat1, b, L0 + u);
  s += f1val(feat1, b, L0 + 4u);
  At[tiled_idx(b * N1 + n, j)] = f2bf(s * 0.1f);
}

// H2all[b][n2][i] = (1/18) sum_{u<18} F2[18*(512*n2+i)+u]
__global__ __launch_bounds__(256) void feat_b_stage1(const float* __restrict__ feat2,
                                                     float* __restrict__ H2all) {
  int b = blockIdx.x / M2;
  int n2 = blockIdx.x % M2;
  for (int i = threadIdx.x; i < 512; i += 256) {
    unsigned L0 = 18u * (unsigned)(512 * n2 + i);
    float s = 0.f;
#pragma unroll
    for (int u = 0; u < 18; ++u) s += f2val(feat2, b, L0 + u);
    H2all[((size_t)b * M2 + n2) * 512 + i] = s * (1.0f / 18.0f);
  }
}

// bilinear 14x14 -> 28x28 over the n2 grid, write feats[b,n,512+i] -> tiled layout
__global__ __launch_bounds__(256) void feat_b_stage2(const float* __restrict__ H2all,
                                                     u16* __restrict__ At) {
  int bn = blockIdx.x;
  int b = bn / N1, n = bn % N1;
  int y = n / 28, x = n % 28;
  float sy = 0.5f * (float)y - 0.25f;
  sy = fminf(fmaxf(sy, 0.f), 13.f);
  int y0 = (int)sy, y1 = min(y0 + 1, 13);
  float wy = sy - (float)y0;
  float sx = 0.5f * (float)x - 0.25f;
  sx = fminf(fmaxf(sx, 0.f), 13.f);
  int x0 = (int)sx, x1 = min(x0 + 1, 13);
  float wx = sx - (float)x0;
  float w00 = (1.f - wy) * (1.f - wx), w10 = wy * (1.f - wx);
  float w01 = (1.f - wy) * wx, w11 = wy * wx;
  const float* h00 = H2all + ((size_t)b * M2 + y0 * 14 + x0) * 512;
  const float* h10 = H2all + ((size_t)b * M2 + y1 * 14 + x0) * 512;
  const float* h01 = H2all + ((size_t)b * M2 + y0 * 14 + x1) * 512;
  const float* h11 = H2all + ((size_t)b * M2 + y1 * 14 + x1) * 512;
  for (int i = threadIdx.x; i < 512; i += 256) {
    float v = w00 * h00[i] + w10 * h10[i] + w01 * h01[i] + w11 * h11[i];
    At[tiled_idx(bn, 512 + i)] = f2bf(v);
  }
}

// memory fp32 -> bf16 tiled; rows [MEMN, MEMNP) = 0. One 8-elem unit per thread,
// dst is exactly linear in thread id (layout nesting == id nesting) -> coalesced writes.
__global__ __launch_bounds__(256) void memconv(const float* __restrict__ mem,
                                               u16* __restrict__ Bt) {
  int gid = blockIdx.x * 256 + threadIdx.x;
  if (gid >= NTILEB * NKB * 512) return;
  int tile = gid >> 14;            // 32*512 units per tile
  int within = gid & 16383;
  int kb = within >> 9;
  int u = within & 511;
  int c = u >> 7, row = u & 127;
  int n = tile * 128 + row;
  int k0 = kb * 32 + c * 8;
  short8v o;
  if (n < MEMN) {
    const float* src = mem + (size_t)n * DIMK + k0;
    float4 a = *(const float4*)src;
    float4 b = *(const float4*)(src + 4);
    o[0] = (short)f2bf(a.x); o[1] = (short)f2bf(a.y);
    o[2] = (short)f2bf(a.z); o[3] = (short)f2bf(a.w);
    o[4] = (short)f2bf(b.x); o[5] = (short)f2bf(b.y);
    o[6] = (short)f2bf(b.z); o[7] = (short)f2bf(b.w);
  } else {
#pragma unroll
    for (int i = 0; i < 8; ++i) o[i] = 0;
  }
  *(short8v*)&Bt[(size_t)gid * 8] = o;
}

// fnorm from tiled bf16 feats: 1 wave per row
__global__ __launch_bounds__(256) void fnorm_bf(const u16* __restrict__ At,
                                                float* __restrict__ fnorm) {
  int row = blockIdx.x * 4 + (threadIdx.x >> 6);
  int lane = threadIdx.x & 63;
  float s = 0.f;
#pragma unroll
  for (int q = 0; q < 2; ++q) {
    int k = (lane + q * 64) * 8;
    short8v v = *(const short8v*)&At[tiled_idx(row, k)];
#pragma unroll
    for (int i = 0; i < 8; ++i) {
      float f = bf2f((u16)v[i]);
      s = fmaf(f, f, s);
    }
  }
#pragma unroll
  for (int off = 32; off; off >>= 1) s += __shfl_down(s, off, 64);
  if (lane == 0) fnorm[row] = s;
}

__global__ __launch_bounds__(256) void mnorm_kernel(const float* __restrict__ memory,
                                                    float* __restrict__ mnorm) {
  __shared__ float red[4];
  const int row = blockIdx.x;
  const float4 v = *(const float4*)&memory[(size_t)row * DIMK + threadIdx.x * 4];
  float s = v.x * v.x + v.y * v.y + v.z * v.z + v.w * v.w;
#pragma unroll
  for (int off = 32; off; off >>= 1) s += __shfl_down(s, off, 64);
  if ((threadIdx.x & 63) == 0) red[threadIdx.x >> 6] = s;
  __syncthreads();
  if (threadIdx.x == 0) mnorm[row] = red[0] + red[1] + red[2] + red[3];
}

// ---- bf16 MFMA distance GEMM + row-min ----
// 128x128 tile, BK=32, 4 waves (2x2), 3-buffer LDS pipeline with counted vmcnt.
// LDS per-tile layout (k-major): [c=4][row=128][8 elems] -> conflict-free ds_read_b128.
__global__ __launch_bounds__(256) void dist_min_mfma(const u16* __restrict__ At,
                                                     const u16* __restrict__ Bt,
                                                     const float* __restrict__ mnorm,
                                                     unsigned int* __restrict__ minu) {
  __shared__ __align__(16) u16 As[3][4096];
  __shared__ __align__(16) u16 Bs[3][4096];
  const int t = threadIdx.x;
  const int wave = t >> 6, lane = t & 63;

  // bijective XCD chunking (m204): q=961, r=5
  int lid = blockIdx.x;
  const int q = NWG / 8, r = NWG % 8;
  int xcd = lid & 7, pos = lid >> 3;
  int wgid = (xcd < r ? xcd * (q + 1) : r * (q + 1) + (xcd - r) * q) + pos;
  // supertile: 7 row-tiles per group (49 = 7*7), rows fastest within a column
  int g = wgid / (NTILEB * 7), rem = wgid % (NTILEB * 7);
  int bx = rem / 7;            // col tile 0..156
  int by = g * 7 + rem % 7;    // row tile 0..48
  const int row0 = by * 128, col0 = bx * 128;

  const u16* Abase = At + (size_t)by * (NKB * 4096);
  const u16* Bbase = Bt + (size_t)bx * (NKB * 4096);

  f32x4 acc[4][4];
#pragma unroll
  for (int i = 0; i < 4; ++i)
#pragma unroll
    for (int j = 0; j < 4; ++j) acc[i][j] = (f32x4){0.f, 0.f, 0.f, 0.f};

  const int wr = (wave >> 1) * 64, wc = (wave & 1) * 64;
  const int frow = lane & 15, fc = lane >> 4;
  const int soff = wave * 512 + lane * 8;   // staging chunk offset (u16) within a 4096-u16 tile

  // stage one K-tile (4 gload16 per thread): src is contiguous (pre-tiled layout)
#define STAGE(kb, buf)                                         \
  do {                                                         \
    const u16* a0 = Abase + (kb) * 4096 + soff;                \
    const u16* b0 = Bbase + (kb) * 4096 + soff;                \
    gload16(a0,        &As[buf][wave * 512]);                  \
    gload16(a0 + 2048, &As[buf][2048 + wave * 512]);           \
    gload16(b0,        &Bs[buf][wave * 512]);                  \
    gload16(b0 + 2048, &Bs[buf][2048 + wave * 512]);           \
  } while (0)

  STAGE(0, 0);
  STAGE(1, 1);
  asm volatile("s_waitcnt vmcnt(4)" ::: "memory");   // tile 0 landed
  __builtin_amdgcn_s_barrier();

  int cur = 0;
  for (int kb = 0; kb < NKB; ++kb) {
    if (kb + 2 < NKB) {
      int nxt = (cur == 0) ? 2 : cur - 1;            // (cur+2)%3
      STAGE(kb + 2, nxt);
    }
    short8v a[4], b[4];
#pragma unroll
    for (int mi = 0; mi < 4; ++mi)
      a[mi] = *(const short8v*)&As[cur][(fc * 128 + wr + mi * 16 + frow) * 8];
#pragma unroll
    for (int ni = 0; ni < 4; ++ni)
      b[ni] = *(const short8v*)&Bs[cur][(fc * 128 + wc + ni * 16 + frow) * 8];
#pragma unroll
    for (int mi = 0; mi < 4; ++mi)
#pragma unroll
      for (int ni = 0; ni < 4; ++ni)
        acc[mi][ni] = __builtin_amdgcn_mfma_f32_16x16x32_bf16(a[mi], b[ni], acc[mi][ni], 0, 0, 0);
    if (kb + 2 < NKB) {
      asm volatile("s_waitcnt vmcnt(4)" ::: "memory");  // tile kb+1 landed (kb+2 still in flight)
    } else {
      asm volatile("s_waitcnt vmcnt(0)" ::: "memory");
    }
    if (kb + 1 < NKB) __builtin_amdgcn_s_barrier();
    cur = (cur == 2) ? 0 : cur + 1;
  }
#undef STAGE

  // epilogue: v = mnorm[col] - 2*dot ; row-min across the 16-lane group
  float cmn[4];
#pragma unroll
  for (int ni = 0; ni < 4; ++ni) {
    int gn = col0 + wc + ni * 16 + frow;
    cmn[ni] = (gn < MEMN) ? mnorm[gn] : INFINITY;
  }
#pragma unroll
  for (int mi = 0; mi < 4; ++mi) {
#pragma unroll
    for (int rr = 0; rr < 4; ++rr) {
      float v = INFINITY;
#pragma unroll
      for (int ni = 0; ni < 4; ++ni)
        v = fminf(v, fmaf(-2.f, acc[mi][ni][rr], cmn[ni]));
#pragma unroll
      for (int off = 1; off < 16; off <<= 1)
        v = fminf(v, __shfl_xor(v, off, 64));
      if (frow == 0) {
        int grow = row0 + wr + mi * 16 + (lane >> 4) * 4 + rr;
        atomicMin(&minu[grow], f2ord(v));
      }
    }
  }
}

// ================= epilogue kernels =================

__global__ __launch_bounds__(256) void scores_kernel(const float* __restrict__ fnorm,
                                                     const unsigned int* __restrict__ minu,
                                                     float* __restrict__ scores) {
  int row = blockIdx.x * 256 + threadIdx.x;
  if (row >= NROWS) return;
  float d2 = fnorm[row] + ord2f(minu[row]);
  scores[row] = sqrtf(fmaxf(d2, 0.f));
}

__global__ __launch_bounds__(256) void image_max_kernel(const float* __restrict__ scores,
                                                        float* __restrict__ out) {
  __shared__ float red[4];
  const int b = blockIdx.x;
  float m = -INFINITY;
  for (int n = threadIdx.x; n < N1; n += 256) m = fmaxf(m, scores[b * N1 + n]);
#pragma unroll
  for (int off = 32; off; off >>= 1) m = fmaxf(m, __shfl_down(m, off, 64));
  if ((threadIdx.x & 63) == 0) red[threadIdx.x >> 6] = m;
  __syncthreads();
  if (threadIdx.x == 0) out[b] = fmaxf(fmaxf(red[0], red[1]), fmaxf(red[2], red[3]));
}

__global__ __launch_bounds__(256) void upsample_kernel(const float* __restrict__ scores,
                                                       float* __restrict__ out) {
  int o = blockIdx.x * 256 + threadIdx.x;
  if (o >= BQ * OUTHW) return;
  int b = o / OUTHW, rem = o % OUTHW;
  int oy = rem / 224, ox = rem % 224;
  float sy = ((float)oy + 0.5f) * 0.125f - 0.5f;
  sy = fminf(fmaxf(sy, 0.f), 27.f);
  int y0 = (int)sy, y1 = min(y0 + 1, 27);
  float wy = sy - (float)y0;
  float sx = ((float)ox + 0.5f) * 0.125f - 0.5f;
  sx = fminf(fmaxf(sx, 0.f), 27.f);
  int x0 = (int)sx, x1 = min(x0 + 1, 27);
  float wx = sx - (float)x0;
  const float* s = scores + b * N1;
  float v0 = s[y0 * 28 + x0] * (1.f - wy) + s[y1 * 28 + x0] * wy;
  float v1 = s[y0 * 28 + x1] * (1.f - wy) + s[y1 * 28 + x1] * wy;
  out[BQ + o] = v0 * (1.f - wx) + v1 * wx;
}

extern "C" void kernel_launch(void* const* d_in, const int* in_sizes, int n_in,
                              void* d_out, int out_size, void* d_ws, size_t ws_size,
                              hipStream_t stream) {
  const float* feat1 = (const float*)d_in[0];
  const float* feat2 = (const float*)d_in[1];
  const float* memory = (const float*)d_in[2];
  float* out = (float*)d_out;

  char* ws = (char*)d_ws;
  size_t off = 0;
  auto wsalloc = [&](size_t bytes) {
    void* p = ws + off;
    off += (bytes + 255) & ~(size_t)255;
    return p;
  };

  u16* At = (u16*)wsalloc((size_t)NROWS * DIMK * 2);
  u16* Bt = (u16*)wsalloc((size_t)MEMNP * DIMK * 2);
  float* H2all = (float*)wsalloc((size_t)BQ * M2 * 512 * 4);
  float* mnorm = (float*)wsalloc((size_t)MEMN * 4);
  float* fnorm = (float*)wsalloc((size_t)NROWS * 4);
  unsigned int* minu = (unsigned int*)wsalloc((size_t)NROWS * 4);
  float* scores = (float*)wsalloc((size_t)NROWS * 4);

  feat_a_bf<<<(BQ * N1 * C1N) / 256, 256, 0, stream>>>(feat1, At);
  feat_b_stage1<<<BQ * M2, 256, 0, stream>>>(feat2, H2all);
  feat_b_stage2<<<BQ * N1, 256, 0, stream>>>(H2all, At);
  memconv<<<(NTILEB * NKB * 512) / 256, 256, 0, stream>>>(memory, Bt);
  fnorm_bf<<<NROWS / 4, 256, 0, stream>>>(At, fnorm);
  mnorm_kernel<<<MEMN, 256, 0, stream>>>(memory, mnorm);
  hipMemsetAsync(minu, 0xFF, (size_t)NROWS * 4, stream);

  dist_min_mfma<<<NWG, 256, 0, stream>>>(At, Bt, mnorm, minu);

  scores_kernel<<<(NROWS + 255) / 256, 256, 0, stream>>>(fnorm, minu, scores);
  image_max_kernel<<<BQ, 256, 0, stream>>>(scores, out);
  upsample_kernel<<<(BQ * OUTHW + 255) / 256, 256, 0, stream>>>(scores, out);
}

// Round 5
// 404.709 us; speedup vs baseline: 7.4816x; 1.1439x over previous
//
#include <hip/hip_runtime.h>
#include <hip/hip_bf16.h>
#include <math.h>

// Problem constants
#define BQ 8
#define C1N 512
#define N1 784          // 28*28
#define C2N 1024
#define M2 196          // 14*14
#define NROWS 6272      // 8*784 = 49*128
#define MEMN 20000
#define MEMNP 20096     // 157*128
#define DIMK 1024
#define NKB 32          // K blocks of 32
#define OUTHW 50176     // 224*224
#define NTILEA 49
#define NTILEB 157
#define NWG (NTILEB * NTILEA)   // 7693

typedef unsigned short u16;
typedef __attribute__((ext_vector_type(8))) short short8v;
typedef __attribute__((ext_vector_type(4))) float f32x4;

// ---- order-preserving float <-> uint for atomicMin ----
static __device__ __forceinline__ unsigned int f2ord(float f) {
  unsigned int b = __float_as_uint(f);
  return (b & 0x80000000u) ? ~b : (b | 0x80000000u);
}
static __device__ __forceinline__ float ord2f(unsigned int u) {
  unsigned int b = (u & 0x80000000u) ? (u ^ 0x80000000u) : ~u;
  return __uint_as_float(b);
}

// ---- bf16 helpers (RNE) ----
static __device__ __forceinline__ u16 f2bf(float x) {
  unsigned u = __float_as_uint(x);
  u += 0x7FFFu + ((u >> 16) & 1u);
  return (u16)(u >> 16);
}
static __device__ __forceinline__ float bf2f(u16 b) {
  return __uint_as_float(((unsigned)b) << 16);
}

// ---- async global->LDS (16B per lane; LDS dest = uniform base + lane*16) ----
static __device__ __forceinline__ void gload16(const void* g, void* l) {
  __builtin_amdgcn_global_load_lds((const __attribute__((address_space(1))) void*)g,
                                   (__attribute__((address_space(3))) void*)l, 16, 0, 0);
}

// ---- tiled (k-major) element index ----
// layout: [tile][kb=32][c=4][row=128][e=8] ; element (grow=tile*128+row, k=kb*32+c*8+e)
static __device__ __forceinline__ size_t tiled_idx(int grow, int k) {
  int tile = grow >> 7, row = grow & 127;
  int kb = k >> 5, c = (k >> 3) & 3, e = k & 7;
  return (((size_t)(tile * NKB + kb) * 4 + c) * 128 + row) * 8 + e;
}

// ---- scrambled patchify flat-index decode ----
// Reference's patchify flattens per-batch in (kj, w, c, ki, h) row-major order:
//   L = (((kj*W + w)*C + c)*3 + ki)*H + h ; value = x[b, c, h+ki-1, w+kj-1] (0 if OOB)
static __device__ __forceinline__ float f1val(const float* __restrict__ x, int b, unsigned L) {
  unsigned h = L % 28u; unsigned t = L / 28u;
  unsigned ki = t % 3u; t /= 3u;
  unsigned c = t % 512u; t /= 512u;
  unsigned w = t % 28u; unsigned kj = t / 28u;
  unsigned y = h + ki - 1u;   // wraps to huge if -1
  unsigned xx = w + kj - 1u;
  if (y >= 28u || xx >= 28u) return 0.f;
  return x[(((size_t)b * 512u + c) * 28u + y) * 28u + xx];
}
static __device__ __forceinline__ float f2val(const float* __restrict__ x, int b, unsigned L) {
  unsigned h = L % 14u; unsigned t = L / 14u;
  unsigned ki = t % 3u; t /= 3u;
  unsigned c = t % 1024u; t /= 1024u;
  unsigned w = t % 14u; unsigned kj = t / 14u;
  unsigned y = h + ki - 1u;
  unsigned xx = w + kj - 1u;
  if (y >= 14u || xx >= 14u) return 0.f;
  return x[(((size_t)b * 1024u + c) * 14u + y) * 14u + xx];
}

// feats[b,n,j<512] = (sum_{u=0..8} F1[9*(512n+j)+u] + F1[...+4]) / 10  -> tiled layout
__global__ __launch_bounds__(256) void feat_a_bf(const float* __restrict__ feat1,
                                                 u16* __restrict__ At) {
  int id = blockIdx.x * 256 + threadIdx.x;
  if (id >= BQ * N1 * C1N) return;
  int j = id & 511; int t = id >> 9;
  int n = t % N1; int b = t / N1;
  unsigned L0 = 9u * (unsigned)(512 * n + j);
  float s = 0.f;
#pragma unroll
  for (int u = 0; u < 9; ++u) s += f1val(feat1, b, L0 + u);
  s += f1val(feat1, b, L0 + 4u);
  At[tiled_idx(b * N1 + n, j)] = f2bf(s * 0.1f);
}

// H2all[b][n2][i] = (1/18) sum_{u<18} F2[18*(512*n2+i)+u]
__global__ __launch_bounds__(256) void feat_b_stage1(const float* __restrict__ feat2,
                                                     float* __restrict__ H2all) {
  int b = blockIdx.x / M2;
  int n2 = blockIdx.x % M2;
  for (int i = threadIdx.x; i < 512; i += 256) {
    unsigned L0 = 18u * (unsigned)(512 * n2 + i);
    float s = 0.f;
#pragma unroll
    for (int u = 0; u < 18; ++u) s += f2val(feat2, b, L0 + u);
    H2all[((size_t)b * M2 + n2) * 512 + i] = s * (1.0f / 18.0f);
  }
}

// bilinear 14x14 -> 28x28 over the n2 grid, write feats[b,n,512+i] -> tiled layout
__global__ __launch_bounds__(256) void feat_b_stage2(const float* __restrict__ H2all,
                                                     u16* __restrict__ At) {
  int bn = blockIdx.x;
  int b = bn / N1, n = bn % N1;
  int y = n / 28, x = n % 28;
  float sy = 0.5f * (float)y - 0.25f;
  sy = fminf(fmaxf(sy, 0.f), 13.f);
  int y0 = (int)sy, y1 = min(y0 + 1, 13);
  float wy = sy - (float)y0;
  float sx = 0.5f * (float)x - 0.25f;
  sx = fminf(fmaxf(sx, 0.f), 13.f);
  int x0 = (int)sx, x1 = min(x0 + 1, 13);
  float wx = sx - (float)x0;
  float w00 = (1.f - wy) * (1.f - wx), w10 = wy * (1.f - wx);
  float w01 = (1.f - wy) * wx, w11 = wy * wx;
  const float* h00 = H2all + ((size_t)b * M2 + y0 * 14 + x0) * 512;
  const float* h10 = H2all + ((size_t)b * M2 + y1 * 14 + x0) * 512;
  const float* h01 = H2all + ((size_t)b * M2 + y0 * 14 + x1) * 512;
  const float* h11 = H2all + ((size_t)b * M2 + y1 * 14 + x1) * 512;
  for (int i = threadIdx.x; i < 512; i += 256) {
    float v = w00 * h00[i] + w10 * h10[i] + w01 * h01[i] + w11 * h11[i];
    At[tiled_idx(bn, 512 + i)] = f2bf(v);
  }
}

// memory fp32 -> bf16 tiled; rows [MEMN, MEMNP) = 0. One 8-elem unit per thread,
// dst is exactly linear in thread id (layout nesting == id nesting) -> coalesced writes.
__global__ __launch_bounds__(256) void memconv(const float* __restrict__ mem,
                                               u16* __restrict__ Bt) {
  int gid = blockIdx.x * 256 + threadIdx.x;
  if (gid >= NTILEB * NKB * 512) return;
  int tile = gid >> 14;            // 32*512 units per tile
  int within = gid & 16383;
  int kb = within >> 9;
  int u = within & 511;
  int c = u >> 7, row = u & 127;
  int n = tile * 128 + row;
  int k0 = kb * 32 + c * 8;
  short8v o;
  if (n < MEMN) {
    const float* src = mem + (size_t)n * DIMK + k0;
    float4 a = *(const float4*)src;
    float4 b = *(const float4*)(src + 4);
    o[0] = (short)f2bf(a.x); o[1] = (short)f2bf(a.y);
    o[2] = (short)f2bf(a.z); o[3] = (short)f2bf(a.w);
    o[4] = (short)f2bf(b.x); o[5] = (short)f2bf(b.y);
    o[6] = (short)f2bf(b.z); o[7] = (short)f2bf(b.w);
  } else {
#pragma unroll
    for (int i = 0; i < 8; ++i) o[i] = 0;
  }
  *(short8v*)&Bt[(size_t)gid * 8] = o;
}

// fnorm from tiled bf16 feats: 1 wave per row
__global__ __launch_bounds__(256) void fnorm_bf(const u16* __restrict__ At,
                                                float* __restrict__ fnorm) {
  int row = blockIdx.x * 4 + (threadIdx.x >> 6);
  int lane = threadIdx.x & 63;
  float s = 0.f;
#pragma unroll
  for (int q = 0; q < 2; ++q) {
    int k = (lane + q * 64) * 8;
    short8v v = *(const short8v*)&At[tiled_idx(row, k)];
#pragma unroll
    for (int i = 0; i < 8; ++i) {
      float f = bf2f((u16)v[i]);
      s = fmaf(f, f, s);
    }
  }
#pragma unroll
  for (int off = 32; off; off >>= 1) s += __shfl_down(s, off, 64);
  if (lane == 0) fnorm[row] = s;
}

__global__ __launch_bounds__(256) void mnorm_kernel(const float* __restrict__ memory,
                                                    float* __restrict__ mnorm) {
  __shared__ float red[4];
  const int row = blockIdx.x;
  const float4 v = *(const float4*)&memory[(size_t)row * DIMK + threadIdx.x * 4];
  float s = v.x * v.x + v.y * v.y + v.z * v.z + v.w * v.w;
#pragma unroll
  for (int off = 32; off; off >>= 1) s += __shfl_down(s, off, 64);
  if ((threadIdx.x & 63) == 0) red[threadIdx.x >> 6] = s;
  __syncthreads();
  if (threadIdx.x == 0) mnorm[row] = red[0] + red[1] + red[2] + red[3];
}

// ---- bf16 MFMA distance GEMM + row-min ----
// 128x128 tile, BK=32, 4 waves (2x2), 3-buffer LDS pipeline with counted vmcnt.
// K-loop unrolled x3 so buffer slots are compile-time constants: ds_read addresses
// become base VGPR + immediate offset, staging pointers bump by constants.
__global__ __launch_bounds__(256, 3) void dist_min_mfma(const u16* __restrict__ At,
                                                        const u16* __restrict__ Bt,
                                                        const float* __restrict__ mnorm,
                                                        unsigned int* __restrict__ minu) {
  __shared__ __align__(16) u16 As[3][4096];
  __shared__ __align__(16) u16 Bs[3][4096];
  const int t = threadIdx.x;
  const int wave = t >> 6, lane = t & 63;

  // bijective XCD chunking (m204): q=961, r=5
  int lid = blockIdx.x;
  const int q = NWG / 8, r = NWG % 8;
  int xcd = lid & 7, pos = lid >> 3;
  int wgid = (xcd < r ? xcd * (q + 1) : r * (q + 1) + (xcd - r) * q) + pos;
  // supertile: 7 row-tiles per group (49 = 7*7), rows fastest within a column
  int g = wgid / (NTILEB * 7), rem = wgid % (NTILEB * 7);
  int bx = rem / 7;            // col tile 0..156
  int by = g * 7 + rem % 7;    // row tile 0..48
  const int row0 = by * 128, col0 = bx * 128;

  f32x4 acc[4][4];
#pragma unroll
  for (int i = 0; i < 4; ++i)
#pragma unroll
    for (int j = 0; j < 4; ++j) acc[i][j] = (f32x4){0.f, 0.f, 0.f, 0.f};

  const int wr = (wave >> 1) * 64, wc = (wave & 1) * 64;
  const int frow = lane & 15, fc = lane >> 4;
  const int soff = wave * 512 + lane * 8;   // staging chunk offset (u16) within a 4096-u16 tile

  const u16* aG = At + (size_t)by * (NKB * 4096) + soff;
  const u16* bG = Bt + (size_t)bx * (NKB * 4096) + soff;

  // stage one K-tile into static buffer slot; advance pointers by one K-tile
#define STAGE(buf)                                   \
  do {                                               \
    gload16(aG,        &As[buf][wave * 512]);        \
    gload16(aG + 2048, &As[buf][2048 + wave * 512]); \
    gload16(bG,        &Bs[buf][wave * 512]);        \
    gload16(bG + 2048, &Bs[buf][2048 + wave * 512]); \
    aG += 4096; bG += 4096;                          \
  } while (0)

  // compute one K-tile from static buffer slot
#define COMPUTE(buf)                                                                         \
  do {                                                                                       \
    short8v a[4], b[4];                                                                      \
    _Pragma("unroll") for (int mi = 0; mi < 4; ++mi)                                         \
        a[mi] = *(const short8v*)&As[buf][(fc * 128 + wr + mi * 16 + frow) * 8];             \
    _Pragma("unroll") for (int ni = 0; ni < 4; ++ni)                                         \
        b[ni] = *(const short8v*)&Bs[buf][(fc * 128 + wc + ni * 16 + frow) * 8];             \
    __builtin_amdgcn_s_setprio(1);                                                           \
    _Pragma("unroll") for (int mi = 0; mi < 4; ++mi)                                         \
      _Pragma("unroll") for (int ni = 0; ni < 4; ++ni)                                       \
          acc[mi][ni] = __builtin_amdgcn_mfma_f32_16x16x32_bf16(a[mi], b[ni], acc[mi][ni],   \
                                                                0, 0, 0);                    \
    __builtin_amdgcn_s_setprio(0);                                                           \
  } while (0)

#define WAITBAR(n)                                        \
  do {                                                    \
    asm volatile("s_waitcnt vmcnt(" #n ")" ::: "memory"); \
    __builtin_amdgcn_s_barrier();                         \
  } while (0)

  STAGE(0);
  STAGE(1);
  WAITBAR(4);   // tile 0 landed, tile 1 in flight

  // main: 10 iterations x 3 static slots = K-tiles 0..29 (prefetch through tile 31)
  for (int i = 0; i < 10; ++i) {
    STAGE(2); COMPUTE(0); WAITBAR(4);
    STAGE(0); COMPUTE(1); WAITBAR(4);
    STAGE(1); COMPUTE(2); WAITBAR(4);
  }
  // tail: K-tiles 30 (buf0), 31 (buf1)
  COMPUTE(0);
  WAITBAR(0);
  COMPUTE(1);
#undef STAGE
#undef COMPUTE
#undef WAITBAR

  // epilogue: v = mnorm[col] - 2*dot ; row-min across the 16-lane group
  float cmn[4];
#pragma unroll
  for (int ni = 0; ni < 4; ++ni) {
    int gn = col0 + wc + ni * 16 + frow;
    cmn[ni] = (gn < MEMN) ? mnorm[gn] : INFINITY;
  }
#pragma unroll
  for (int mi = 0; mi < 4; ++mi) {
#pragma unroll
    for (int rr = 0; rr < 4; ++rr) {
      float v = INFINITY;
#pragma unroll
      for (int ni = 0; ni < 4; ++ni)
        v = fminf(v, fmaf(-2.f, acc[mi][ni][rr], cmn[ni]));
#pragma unroll
      for (int off = 1; off < 16; off <<= 1)
        v = fminf(v, __shfl_xor(v, off, 64));
      if (frow == 0) {
        int grow = row0 + wr + mi * 16 + (lane >> 4) * 4 + rr;
        atomicMin(&minu[grow], f2ord(v));
      }
    }
  }
}

// ================= epilogue kernels =================

__global__ __launch_bounds__(256) void scores_kernel(const float* __restrict__ fnorm,
                                                     const unsigned int* __restrict__ minu,
                                                     float* __restrict__ scores) {
  int row = blockIdx.x * 256 + threadIdx.x;
  if (row >= NROWS) return;
  float d2 = fnorm[row] + ord2f(minu[row]);
  scores[row] = sqrtf(fmaxf(d2, 0.f));
}

__global__ __launch_bounds__(256) void image_max_kernel(const float* __restrict__ scores,
                                                        float* __restrict__ out) {
  __shared__ float red[4];
  const int b = blockIdx.x;
  float m = -INFINITY;
  for (int n = threadIdx.x; n < N1; n += 256) m = fmaxf(m, scores[b * N1 + n]);
#pragma unroll
  for (int off = 32; off; off >>= 1) m = fmaxf(m, __shfl_down(m, off, 64));
  if ((threadIdx.x & 63) == 0) red[threadIdx.x >> 6] = m;
  __syncthreads();
  if (threadIdx.x == 0) out[b] = fmaxf(fmaxf(red[0], red[1]), fmaxf(red[2], red[3]));
}

__global__ __launch_bounds__(256) void upsample_kernel(const float* __restrict__ scores,
                                                       float* __restrict__ out) {
  int o = blockIdx.x * 256 + threadIdx.x;
  if (o >= BQ * OUTHW) return;
  int b = o / OUTHW, rem = o % OUTHW;
  int oy = rem / 224, ox = rem % 224;
  float sy = ((float)oy + 0.5f) * 0.125f - 0.5f;
  sy = fminf(fmaxf(sy, 0.f), 27.f);
  int y0 = (int)sy, y1 = min(y0 + 1, 27);
  float wy = sy - (float)y0;
  float sx = ((float)ox + 0.5f) * 0.125f - 0.5f;
  sx = fminf(fmaxf(sx, 0.f), 27.f);
  int x0 = (int)sx, x1 = min(x0 + 1, 27);
  float wx = sx - (float)x0;
  const float* s = scores + b * N1;
  float v0 = s[y0 * 28 + x0] * (1.f - wy) + s[y1 * 28 + x0] * wy;
  float v1 = s[y0 * 28 + x1] * (1.f - wy) + s[y1 * 28 + x1] * wy;
  out[BQ + o] = v0 * (1.f - wx) + v1 * wx;
}

extern "C" void kernel_launch(void* const* d_in, const int* in_sizes, int n_in,
                              void* d_out, int out_size, void* d_ws, size_t ws_size,
                              hipStream_t stream) {
  const float* feat1 = (const float*)d_in[0];
  const float* feat2 = (const float*)d_in[1];
  const float* memory = (const float*)d_in[2];
  float* out = (float*)d_out;

  char* ws = (char*)d_ws;
  size_t off = 0;
  auto wsalloc = [&](size_t bytes) {
    void* p = ws + off;
    off += (bytes + 255) & ~(size_t)255;
    return p;
  };

  u16* At = (u16*)wsalloc((size_t)NROWS * DIMK * 2);
  u16* Bt = (u16*)wsalloc((size_t)MEMNP * DIMK * 2);
  float* H2all = (float*)wsalloc((size_t)BQ * M2 * 512 * 4);
  float* mnorm = (float*)wsalloc((size_t)MEMN * 4);
  float* fnorm = (float*)wsalloc((size_t)NROWS * 4);
  unsigned int* minu = (unsigned int*)wsalloc((size_t)NROWS * 4);
  float* scores = (float*)wsalloc((size_t)NROWS * 4);

  feat_a_bf<<<(BQ * N1 * C1N) / 256, 256, 0, stream>>>(feat1, At);
  feat_b_stage1<<<BQ * M2, 256, 0, stream>>>(feat2, H2all);
  feat_b_stage2<<<BQ * N1, 256, 0, stream>>>(H2all, At);
  memconv<<<(NTILEB * NKB * 512) / 256, 256, 0, stream>>>(memory, Bt);
  fnorm_bf<<<NROWS / 4, 256, 0, stream>>>(At, fnorm);
  mnorm_kernel<<<MEMN, 256, 0, stream>>>(memory, mnorm);
  hipMemsetAsync(minu, 0xFF, (size_t)NROWS * 4, stream);

  dist_min_mfma<<<NWG, 256, 0, stream>>>(At, Bt, mnorm, minu);

  scores_kernel<<<(NROWS + 255) / 256, 256, 0, stream>>>(fnorm, minu, scores);
  image_max_kernel<<<BQ, 256, 0, stream>>>(scores, out);
  upsample_kernel<<<(BQ * OUTHW + 255) / 256, 256, 0, stream>>>(scores, out);
}